// Round 4
// baseline (2032.752 us; speedup 1.0000x reference)
//
#include <hip/hip_runtime.h>
#include <cstdint>
#include <cmath>

// Problem constants (fixed by reference):
//   B=64 examples, D=128 dim, NP=512 nodes/tokens per example, 100 Jacobi Sinkhorn iters.
#define NB_EX 64
#define DIMD 128
#define NP 512
#define NITER 100
constexpr float MARG = 1.0f / 512.0f;   // a = b = 1/n

// ---------- helpers ----------
__device__ __forceinline__ float bf2f_lo(unsigned w) { return __uint_as_float(w << 16); }
__device__ __forceinline__ float bf2f_hi(unsigned w) { return __uint_as_float(w & 0xFFFF0000u); }
__device__ __forceinline__ unsigned short f2bf(float f) {
    unsigned u = __float_as_uint(f);
    u += 0x7FFFu + ((u >> 16) & 1u);      // RTNE
    return (unsigned short)(u >> 16);
}
__device__ __forceinline__ float wred64(float v) {
#pragma unroll
    for (int m = 1; m < 64; m <<= 1) v += __shfl_xor(v, m, 64);
    return v;
}

// ---------- workspace layout (bytes) ----------
// 0        : flag (int)  dtype detector result
// 64       : ctr[64] per-example barrier counters, stride 64 B (4096 B)
// 16640    : simg     64*64 f32 logits (16384)
#define O_SIMG   16640
#define O_RNSG   33024
#define O_RNQG   33280
#define O_RNAN   33536
#define O_RNBN   164608
#define O_COLP   295680          // 2 banks x 64ex x 8blk x 512 f32 (2097152)
#define O_P0     2621440         // 64*512*512 bf16 (33554432) -> total ~36.2 MB
#define COLP_BANK (64 * 8 * 512) // floats per bank

// ---------- dtype detector + output zero-init + barrier counter zero ----------
__global__ void k_detect(const unsigned* in0, int* flag, float* outf, unsigned* ctr) {
    __shared__ int cnt;
    if (threadIdx.x == 0) cnt = 0;
    __syncthreads();
    unsigned w = in0[threadIdx.x];          // first 1KB; buffer >= 16 KB either way
    unsigned e = (w >> 7) & 0xFFu;          // exponent field of low bf16 (if bf16)
    if (e >= 110u && e <= 130u) atomicAdd(&cnt, 1);
    __syncthreads();
    if (threadIdx.x == 0) *flag = (cnt >= 128) ? 1 : 0;
    if (threadIdx.x < 3) outf[threadIdx.x] = 0.0f;   // d_out re-poisoned before every call
    if (threadIdx.x < 64) ctr[threadIdx.x * 16] = 0u;
}

// ---------- inverse L2 norms per row (128-dim rows), one wave per row ----------
__global__ void k_rnorm(const void* in, float* rn, int rows, const int* flagp) {
    int flag = *flagp;
    int row  = blockIdx.x * 4 + (threadIdx.x >> 6);
    int lane = threadIdx.x & 63;
    if (row >= rows) return;
    float f0, f1;
    if (flag) {
        unsigned w = ((const unsigned*)in)[row * 64 + lane];
        f0 = bf2f_lo(w); f1 = bf2f_hi(w);
    } else {
        float2 v = ((const float2*)in)[row * 64 + lane];
        f0 = v.x; f1 = v.y;
    }
    float ss = wred64(f0 * f0 + f1 * f1);
    if (lane == 0) rn[row] = 1.0f / fmaxf(sqrtf(ss), 1e-12f);
}

// ---------- global sim logits: simg[i][j] = (s_i . q_j) * rn_i * rn_j / TEMP ----------
__global__ void k_simg(const void* sgr, const void* qgr, const float* rnsg, const float* rnqg,
                       float* simg, const int* flagp) {
    int flag = *flagp;
    int g = blockIdx.x * 256 + threadIdx.x;     // 4096 = 64*64
    int i = g >> 6, j = g & 63;
    float dot = 0.f;
    if (flag) {
        const unsigned* a = (const unsigned*)sgr + i * 64;
        const unsigned* b = (const unsigned*)qgr + j * 64;
        for (int k = 0; k < 64; k++) {
            unsigned wa = a[k], wb = b[k];
            dot += bf2f_lo(wa) * bf2f_lo(wb);
            dot += bf2f_hi(wa) * bf2f_hi(wb);
        }
    } else {
        const float4* a = (const float4*)sgr + i * 32;
        const float4* b = (const float4*)qgr + j * 32;
        for (int k = 0; k < 32; k++) {
            float4 x = a[k], y = b[k];
            dot += x.x * y.x + x.y * y.y + x.z * y.z + x.w * y.w;
        }
    }
    simg[g] = dot * rnsg[i] * rnqg[j] * 10.0f;   // /TEMP = *10
}

// ---------- global NT-Xent from sim logits; writes outf[0] and adds to outf[2] ----------
__global__ void k_gloss(const float* __restrict__ simg, float* outf) {
    __shared__ float red[64];
    int i = threadIdx.x;
    if (i < 64) {
        float m = -1e30f;
        for (int j = 0; j < 64; j++) m = fmaxf(m, simg[i * 64 + j]);
        float se = 0.f;
        for (int j = 0; j < 64; j++) se += expf(simg[i * 64 + j] - m);
        float rl = simg[i * 64 + i] - (m + logf(se));
        float m2 = -1e30f;
        for (int j = 0; j < 64; j++) m2 = fmaxf(m2, simg[j * 64 + i]);
        float se2 = 0.f;
        for (int j = 0; j < 64; j++) se2 += expf(simg[j * 64 + i] - m2);
        float cl = simg[i * 64 + i] - (m2 + logf(se2));
        red[i] = rl + cl;
    }
    __syncthreads();
    if (i == 0) {
        float s = 0.f;
        for (int k = 0; k < 64; k++) s += red[k];
        float g = -s / 128.0f;
        atomicAdd(&outf[0], g);
        atomicAdd(&outf[2], g);
    }
}

// ---------- build P0 = exp(10*sim) bf16, per-example 512x512, 128x128 tiles ----------
__global__ void k_build(const void* anr, const void* bnr, const float* rnan, const float* rnbn,
                        unsigned short* p0, const int* flagp) {
    int flag = *flagp;
    int b   = blockIdx.y;
    int r0t = (blockIdx.x >> 2) * 128;
    int c0t = (blockIdx.x & 3) * 128;
    __shared__ float As[128][33];
    __shared__ float Bs[128][33];
    int t  = threadIdx.x;
    int tr = t >> 4, tc = t & 15;
    float acc[8][8];
#pragma unroll
    for (int i = 0; i < 8; i++)
#pragma unroll
        for (int j = 0; j < 8; j++) acc[i][j] = 0.f;

    for (int kc = 0; kc < 4; kc++) {            // K chunks of 32
        for (int ii = 0; ii < 4; ii++) {
            int idx = t + 256 * ii;             // 0..1023 -> 128 rows x 8 float4
            int r = idx >> 3, c4 = idx & 7;
            {   // A chunk (struct_nodes)
                int grow = b * NP + r0t + r;
                float sc = rnan[grow];
                float f0, f1, f2, f3;
                if (flag) {
                    const unsigned* src = (const unsigned*)anr + ((grow * DIMD + kc * 32 + c4 * 4) >> 1);
                    unsigned w0 = src[0], w1 = src[1];
                    f0 = bf2f_lo(w0); f1 = bf2f_hi(w0); f2 = bf2f_lo(w1); f3 = bf2f_hi(w1);
                } else {
                    float4 v = *((const float4*)((const float*)anr + grow * DIMD + kc * 32 + c4 * 4));
                    f0 = v.x; f1 = v.y; f2 = v.z; f3 = v.w;
                }
                As[r][c4 * 4 + 0] = f0 * sc; As[r][c4 * 4 + 1] = f1 * sc;
                As[r][c4 * 4 + 2] = f2 * sc; As[r][c4 * 4 + 3] = f3 * sc;
            }
            {   // B chunk (seq_tokens)
                int grow = b * NP + c0t + r;
                float sc = rnbn[grow];
                float f0, f1, f2, f3;
                if (flag) {
                    const unsigned* src = (const unsigned*)bnr + ((grow * DIMD + kc * 32 + c4 * 4) >> 1);
                    unsigned w0 = src[0], w1 = src[1];
                    f0 = bf2f_lo(w0); f1 = bf2f_hi(w0); f2 = bf2f_lo(w1); f3 = bf2f_hi(w1);
                } else {
                    float4 v = *((const float4*)((const float*)bnr + grow * DIMD + kc * 32 + c4 * 4));
                    f0 = v.x; f1 = v.y; f2 = v.z; f3 = v.w;
                }
                Bs[r][c4 * 4 + 0] = f0 * sc; Bs[r][c4 * 4 + 1] = f1 * sc;
                Bs[r][c4 * 4 + 2] = f2 * sc; Bs[r][c4 * 4 + 3] = f3 * sc;
            }
        }
        __syncthreads();
        for (int kk = 0; kk < 32; kk++) {
            float av[8], bv[8];
#pragma unroll
            for (int i = 0; i < 8; i++) av[i] = As[tr * 8 + i][kk];
#pragma unroll
            for (int j = 0; j < 8; j++) bv[j] = Bs[tc * 8 + j][kk];
#pragma unroll
            for (int i = 0; i < 8; i++)
#pragma unroll
                for (int j = 0; j < 8; j++) acc[i][j] += av[i] * bv[j];
        }
        __syncthreads();
    }
#pragma unroll
    for (int i = 0; i < 8; i++) {
        int grow = b * NP + r0t + tr * 8 + i;
        unsigned short h[8];
#pragma unroll
        for (int j = 0; j < 8; j++) h[j] = f2bf(expf(acc[i][j] * 10.0f));   // exp(sim/REG)
        uint4 pk;
        pk.x = (unsigned)h[0] | ((unsigned)h[1] << 16);
        pk.y = (unsigned)h[2] | ((unsigned)h[3] << 16);
        pk.z = (unsigned)h[4] | ((unsigned)h[5] << 16);
        pk.w = (unsigned)h[6] | ((unsigned)h[7] << 16);
        *((uint4*)(p0 + ((size_t)grow * NP + c0t + tc * 8))) = pk;
    }
}

// ---------- persistent Sinkhorn: 100 Jacobi iters + final contraction in ONE kernel ----------
// PLAIN launch (cooperative launch returned an error in R3 and never ran).
// Co-residency by capacity: 512 blocks x 256 thr, ~10.6 KB LDS, VGPR<=256 cap -> 2 blocks/CU
// fit (8/32 wave slots, 21/160 KB LDS); CP places all 512 at t=0; no block retires early.
// Cross-block sync: per-example monotonic counter barrier (8 blocks/example), agent-scope
// release/acquire atomics handle cross-XCD L2 writeback/invalidate. colpart double-buffered
// by iteration parity (bank k reused at k+2, provably after all readers passed barrier k+1).
__global__ __launch_bounds__(256, 2) void k_persist(const unsigned short* __restrict__ p0,
                                                    float* __restrict__ colp,
                                                    unsigned* __restrict__ ctr,
                                                    float* __restrict__ outf) {
    int blk = blockIdx.x;
    int rb  = blk >> 6;         // 0..7
    int b   = blk & 63;         // example
    int rowbase = rb * 64;
    int t = threadIdx.x, w = t >> 6, lane = t & 63;

    __shared__ float v_s[512];
    __shared__ float u_s[64];
    __shared__ float rowraw[64];
    __shared__ float colred[4][512];
    __shared__ float bs[4];

    // load this lane's static P0 slice into registers (only global P0 read of the kernel)
    uint4 pw[16];
#pragma unroll
    for (int r = 0; r < 16; r++) {
        int row = rowbase + w * 16 + r;
        pw[r] = ((const uint4*)(p0 + (((size_t)(b << 9) + row) << 9)))[lane];
    }
    for (int j = t; j < 512; j += 256) v_s[j] = MARG;
    if (t < 64) u_s[t] = MARG;
    __syncthreads();

    unsigned* myctr = &ctr[b * 16];

#pragma unroll 1
    for (int it = 0; it < NITER; ++it) {
        float vr[8];
#pragma unroll
        for (int k = 0; k < 8; k++) vr[k] = v_s[lane * 8 + k];
        float ca[8];
#pragma unroll
        for (int k = 0; k < 8; k++) ca[k] = 0.f;
#pragma unroll
        for (int r = 0; r < 16; r++) {
            float u_r = u_s[w * 16 + r];
            uint4 pwv = pw[r];
            float f[8];
            f[0] = bf2f_lo(pwv.x); f[1] = bf2f_hi(pwv.x);
            f[2] = bf2f_lo(pwv.y); f[3] = bf2f_hi(pwv.y);
            f[4] = bf2f_lo(pwv.z); f[5] = bf2f_hi(pwv.z);
            f[6] = bf2f_lo(pwv.w); f[7] = bf2f_hi(pwv.w);
            float rd = 0.f;
#pragma unroll
            for (int k = 0; k < 8; k++) { rd += f[k] * vr[k]; ca[k] += f[k] * u_r; }
            rd = wred64(rd);
            if (lane == 0) rowraw[w * 16 + r] = rd;
        }
#pragma unroll
        for (int k = 0; k < 8; k++) colred[w][lane * 8 + k] = ca[k];
        __syncthreads();                                   // rowraw + colred ready
        float* cw = colp + ((((it & 1) * 64 + b) * 8 + rb) << 9);
        for (int j = t; j < 512; j += 256)
            cw[j] = colred[0][j] + colred[1][j] + colred[2][j] + colred[3][j];
        if (t < 64) {                                      // u update from own raw row sums
            float q = MARG / rowraw[t];
            if (!isfinite(q)) q = MARG;
            u_s[t] = q;
        }
        __syncthreads();                                   // drains vmcnt: stores left the CU
        if (t == 0) {
            __hip_atomic_fetch_add(myctr, 1u, __ATOMIC_RELEASE, __HIP_MEMORY_SCOPE_AGENT);
            unsigned tgt = 8u * (unsigned)(it + 1);
            while (__hip_atomic_load(myctr, __ATOMIC_ACQUIRE, __HIP_MEMORY_SCOPE_AGENT) < tgt)
                __builtin_amdgcn_s_sleep(8);
        }
        __syncthreads();
        const float* crd = colp + ((((it & 1) * 64 + b) * 8) << 9);
        for (int j = t; j < 512; j += 256) {               // v update from 8 partials
            float raw = 0.f;
#pragma unroll
            for (int p = 0; p < 8; p++) raw += crd[(p << 9) + j];
            float q = MARG / raw;
            if (!isfinite(q)) q = MARG;
            v_s[j] = q;
        }
        __syncthreads();
    }

    // final contraction: P = u P0 v ; C = -0.1*log(P0)
    float vr[8];
#pragma unroll
    for (int k = 0; k < 8; k++) vr[k] = v_s[lane * 8 + k];
    float acc = 0.f;
#pragma unroll
    for (int r = 0; r < 16; r++) {
        float u_r = u_s[w * 16 + r];
        uint4 pwv = pw[r];
        float f[8];
        f[0] = bf2f_lo(pwv.x); f[1] = bf2f_hi(pwv.x);
        f[2] = bf2f_lo(pwv.y); f[3] = bf2f_hi(pwv.y);
        f[4] = bf2f_lo(pwv.z); f[5] = bf2f_hi(pwv.z);
        f[6] = bf2f_lo(pwv.w); f[7] = bf2f_hi(pwv.w);
#pragma unroll
        for (int k = 0; k < 8; k++) {
            float p = f[k];
            acc += u_r * p * vr[k] * (-0.1f) * logf(p);
        }
    }
    acc = wred64(acc);
    if (lane == 0) bs[w] = acc;
    __syncthreads();
    if (t == 0) {
        float c = (bs[0] + bs[1] + bs[2] + bs[3]) * (1.0f / 64.0f);   // /B
        atomicAdd(&outf[1], c);
        atomicAdd(&outf[2], c);
    }
}

extern "C" void kernel_launch(void* const* d_in, const int* in_sizes, int n_in,
                              void* d_out, int out_size, void* d_ws, size_t ws_size,
                              hipStream_t stream) {
    const void* sg = d_in[0];
    const void* qg = d_in[1];
    const void* an = d_in[2];
    const void* bn = d_in[3];
    char* ws = (char*)d_ws;
    float* outf = (float*)d_out;                     // output dtype: float32 x3

    int*      flagp = (int*)ws;
    unsigned* ctr   = (unsigned*)(ws + 64);
    float* simg     = (float*)(ws + O_SIMG);
    float* rnsg     = (float*)(ws + O_RNSG);
    float* rnqg     = (float*)(ws + O_RNQG);
    float* rnan     = (float*)(ws + O_RNAN);
    float* rnbn     = (float*)(ws + O_RNBN);
    float* colp     = (float*)(ws + O_COLP);         // 2 banks
    unsigned short* p0 = (unsigned short*)(ws + O_P0);

    k_detect<<<1, 256, 0, stream>>>((const unsigned*)sg, flagp, outf, ctr);
    k_rnorm<<<16, 256, 0, stream>>>(sg, rnsg, 64, flagp);
    k_rnorm<<<16, 256, 0, stream>>>(qg, rnqg, 64, flagp);
    k_rnorm<<<8192, 256, 0, stream>>>(an, rnan, 32768, flagp);
    k_rnorm<<<8192, 256, 0, stream>>>(bn, rnbn, 32768, flagp);
    k_simg<<<16, 256, 0, stream>>>(sg, qg, rnsg, rnqg, simg, flagp);
    k_gloss<<<1, 256, 0, stream>>>(simg, outf);
    k_build<<<dim3(16, 64), 256, 0, stream>>>(an, bn, rnan, rnbn, p0, flagp);

    k_persist<<<512, 256, 0, stream>>>(p0, colp, ctr, outf);
}

// Round 5
// 890.163 us; speedup vs baseline: 2.2836x; 2.2836x over previous
//
#include <hip/hip_runtime.h>
#include <cstdint>
#include <cmath>

// Problem constants (fixed by reference):
//   B=64 examples, D=128 dim, NP=512 nodes/tokens per example, 100 Jacobi Sinkhorn iters.
#define NB_EX 64
#define DIMD 128
#define NP 512
#define NITER 100
constexpr float MARG = 1.0f / 512.0f;   // a = b = 1/n

// ---------- helpers ----------
__device__ __forceinline__ float bf2f_lo(unsigned w) { return __uint_as_float(w << 16); }
__device__ __forceinline__ float bf2f_hi(unsigned w) { return __uint_as_float(w & 0xFFFF0000u); }
__device__ __forceinline__ unsigned short f2bf(float f) {
    unsigned u = __float_as_uint(f);
    u += 0x7FFFu + ((u >> 16) & 1u);      // RTNE
    return (unsigned short)(u >> 16);
}
__device__ __forceinline__ float wred64(float v) {
#pragma unroll
    for (int m = 1; m < 64; m <<= 1) v += __shfl_xor(v, m, 64);
    return v;
}

// ---------- workspace layout (bytes) ----------
// 0        : flag (int)  dtype detector result
// 64       : ctr[64] per-example barrier counters, stride 64 B (4096 B)
// 16640    : simg     64*64 f32 logits (16384)
#define O_SIMG   16640
#define O_RNSG   33024
#define O_RNQG   33280
#define O_RNAN   33536
#define O_RNBN   164608
#define O_COLP   295680          // 2 banks x 64ex x 8blk x 512 f32 (2097152)
#define O_P0     2621440         // 64*512*512 bf16 (33554432) -> total ~36.2 MB
#define COLP_BANK (64 * 8 * 512) // floats per bank

// ---------- dtype detector + output zero-init + barrier counter zero ----------
__global__ void k_detect(const unsigned* in0, int* flag, float* outf, unsigned* ctr) {
    __shared__ int cnt;
    if (threadIdx.x == 0) cnt = 0;
    __syncthreads();
    unsigned w = in0[threadIdx.x];          // first 1KB; buffer >= 16 KB either way
    unsigned e = (w >> 7) & 0xFFu;          // exponent field of low bf16 (if bf16)
    if (e >= 110u && e <= 130u) atomicAdd(&cnt, 1);
    __syncthreads();
    if (threadIdx.x == 0) *flag = (cnt >= 128) ? 1 : 0;
    if (threadIdx.x < 3) outf[threadIdx.x] = 0.0f;   // d_out re-poisoned before every call
    if (threadIdx.x < 64)
        __hip_atomic_store(&ctr[threadIdx.x * 16], 0u, __ATOMIC_RELAXED, __HIP_MEMORY_SCOPE_AGENT);
}

// ---------- inverse L2 norms per row (128-dim rows), one wave per row ----------
__global__ void k_rnorm(const void* in, float* rn, int rows, const int* flagp) {
    int flag = *flagp;
    int row  = blockIdx.x * 4 + (threadIdx.x >> 6);
    int lane = threadIdx.x & 63;
    if (row >= rows) return;
    float f0, f1;
    if (flag) {
        unsigned w = ((const unsigned*)in)[row * 64 + lane];
        f0 = bf2f_lo(w); f1 = bf2f_hi(w);
    } else {
        float2 v = ((const float2*)in)[row * 64 + lane];
        f0 = v.x; f1 = v.y;
    }
    float ss = wred64(f0 * f0 + f1 * f1);
    if (lane == 0) rn[row] = 1.0f / fmaxf(sqrtf(ss), 1e-12f);
}

// ---------- global sim logits: simg[i][j] = (s_i . q_j) * rn_i * rn_j / TEMP ----------
__global__ void k_simg(const void* sgr, const void* qgr, const float* rnsg, const float* rnqg,
                       float* simg, const int* flagp) {
    int flag = *flagp;
    int g = blockIdx.x * 256 + threadIdx.x;     // 4096 = 64*64
    int i = g >> 6, j = g & 63;
    float dot = 0.f;
    if (flag) {
        const unsigned* a = (const unsigned*)sgr + i * 64;
        const unsigned* b = (const unsigned*)qgr + j * 64;
        for (int k = 0; k < 64; k++) {
            unsigned wa = a[k], wb = b[k];
            dot += bf2f_lo(wa) * bf2f_lo(wb);
            dot += bf2f_hi(wa) * bf2f_hi(wb);
        }
    } else {
        const float4* a = (const float4*)sgr + i * 32;
        const float4* b = (const float4*)qgr + j * 32;
        for (int k = 0; k < 32; k++) {
            float4 x = a[k], y = b[k];
            dot += x.x * y.x + x.y * y.y + x.z * y.z + x.w * y.w;
        }
    }
    simg[g] = dot * rnsg[i] * rnqg[j] * 10.0f;   // /TEMP = *10
}

// ---------- global NT-Xent from sim logits; writes outf[0] and adds to outf[2] ----------
__global__ void k_gloss(const float* __restrict__ simg, float* outf) {
    __shared__ float red[64];
    int i = threadIdx.x;
    if (i < 64) {
        float m = -1e30f;
        for (int j = 0; j < 64; j++) m = fmaxf(m, simg[i * 64 + j]);
        float se = 0.f;
        for (int j = 0; j < 64; j++) se += expf(simg[i * 64 + j] - m);
        float rl = simg[i * 64 + i] - (m + logf(se));
        float m2 = -1e30f;
        for (int j = 0; j < 64; j++) m2 = fmaxf(m2, simg[j * 64 + i]);
        float se2 = 0.f;
        for (int j = 0; j < 64; j++) se2 += expf(simg[j * 64 + i] - m2);
        float cl = simg[i * 64 + i] - (m2 + logf(se2));
        red[i] = rl + cl;
    }
    __syncthreads();
    if (i == 0) {
        float s = 0.f;
        for (int k = 0; k < 64; k++) s += red[k];
        float g = -s / 128.0f;
        atomicAdd(&outf[0], g);
        atomicAdd(&outf[2], g);
    }
}

// ---------- build P0 = exp(10*sim) bf16, per-example 512x512, 128x128 tiles ----------
__global__ void k_build(const void* anr, const void* bnr, const float* rnan, const float* rnbn,
                        unsigned short* p0, const int* flagp) {
    int flag = *flagp;
    int b   = blockIdx.y;
    int r0t = (blockIdx.x >> 2) * 128;
    int c0t = (blockIdx.x & 3) * 128;
    __shared__ float As[128][33];
    __shared__ float Bs[128][33];
    int t  = threadIdx.x;
    int tr = t >> 4, tc = t & 15;
    float acc[8][8];
#pragma unroll
    for (int i = 0; i < 8; i++)
#pragma unroll
        for (int j = 0; j < 8; j++) acc[i][j] = 0.f;

    for (int kc = 0; kc < 4; kc++) {            // K chunks of 32
        for (int ii = 0; ii < 4; ii++) {
            int idx = t + 256 * ii;             // 0..1023 -> 128 rows x 8 float4
            int r = idx >> 3, c4 = idx & 7;
            {   // A chunk (struct_nodes)
                int grow = b * NP + r0t + r;
                float sc = rnan[grow];
                float f0, f1, f2, f3;
                if (flag) {
                    const unsigned* src = (const unsigned*)anr + ((grow * DIMD + kc * 32 + c4 * 4) >> 1);
                    unsigned w0 = src[0], w1 = src[1];
                    f0 = bf2f_lo(w0); f1 = bf2f_hi(w0); f2 = bf2f_lo(w1); f3 = bf2f_hi(w1);
                } else {
                    float4 v = *((const float4*)((const float*)anr + grow * DIMD + kc * 32 + c4 * 4));
                    f0 = v.x; f1 = v.y; f2 = v.z; f3 = v.w;
                }
                As[r][c4 * 4 + 0] = f0 * sc; As[r][c4 * 4 + 1] = f1 * sc;
                As[r][c4 * 4 + 2] = f2 * sc; As[r][c4 * 4 + 3] = f3 * sc;
            }
            {   // B chunk (seq_tokens)
                int grow = b * NP + c0t + r;
                float sc = rnbn[grow];
                float f0, f1, f2, f3;
                if (flag) {
                    const unsigned* src = (const unsigned*)bnr + ((grow * DIMD + kc * 32 + c4 * 4) >> 1);
                    unsigned w0 = src[0], w1 = src[1];
                    f0 = bf2f_lo(w0); f1 = bf2f_hi(w0); f2 = bf2f_lo(w1); f3 = bf2f_hi(w1);
                } else {
                    float4 v = *((const float4*)((const float*)bnr + grow * DIMD + kc * 32 + c4 * 4));
                    f0 = v.x; f1 = v.y; f2 = v.z; f3 = v.w;
                }
                Bs[r][c4 * 4 + 0] = f0 * sc; Bs[r][c4 * 4 + 1] = f1 * sc;
                Bs[r][c4 * 4 + 2] = f2 * sc; Bs[r][c4 * 4 + 3] = f3 * sc;
            }
        }
        __syncthreads();
        for (int kk = 0; kk < 32; kk++) {
            float av[8], bv[8];
#pragma unroll
            for (int i = 0; i < 8; i++) av[i] = As[tr * 8 + i][kk];
#pragma unroll
            for (int j = 0; j < 8; j++) bv[j] = Bs[tc * 8 + j][kk];
#pragma unroll
            for (int i = 0; i < 8; i++)
#pragma unroll
                for (int j = 0; j < 8; j++) acc[i][j] += av[i] * bv[j];
        }
        __syncthreads();
    }
#pragma unroll
    for (int i = 0; i < 8; i++) {
        int grow = b * NP + r0t + tr * 8 + i;
        unsigned short h[8];
#pragma unroll
        for (int j = 0; j < 8; j++) h[j] = f2bf(expf(acc[i][j] * 10.0f));   // exp(sim/REG)
        uint4 pk;
        pk.x = (unsigned)h[0] | ((unsigned)h[1] << 16);
        pk.y = (unsigned)h[2] | ((unsigned)h[3] << 16);
        pk.z = (unsigned)h[4] | ((unsigned)h[5] << 16);
        pk.w = (unsigned)h[6] | ((unsigned)h[7] << 16);
        *((uint4*)(p0 + ((size_t)grow * NP + c0t + tc * 8))) = pk;
    }
}

// ---------- persistent Sinkhorn: 100 Jacobi iters + final contraction in ONE kernel ----------
// Plain launch; co-residency by capacity (512 blocks x 256 thr, 2 blocks/CU fit trivially).
// R4 lesson: ACQUIRE/RELEASE at agent scope emit buffer_inv / buffer_wbl2 (whole-L2
// invalidate/writeback) -> 18 us/iter of cache-maintenance stalls + 104 MB HBM write-through.
// Fix: ALL cross-block data (colpart, counter) moves via RELAXED agent-scope atomics, which
// compile to single cache-bypassing global ops against the Infinity Cache (device coherence
// point) with NO flush instructions. Ordering: __syncthreads() between colpart stores and the
// counter bump drains vmcnt(0), so partials are globally visible before the counter is.
// colpart double-buffered by iteration parity (bank k reused at k+2, provably after all
// readers of bank k passed barrier k+1 — monotone counter).
__global__ __launch_bounds__(256, 2) void k_persist(const unsigned short* __restrict__ p0,
                                                    float* __restrict__ colp,
                                                    unsigned* __restrict__ ctr,
                                                    float* __restrict__ outf) {
    int blk = blockIdx.x;
    int rb  = blk >> 6;         // 0..7
    int b   = blk & 63;         // example
    int rowbase = rb * 64;
    int t = threadIdx.x, w = t >> 6, lane = t & 63;

    __shared__ float v_s[512];
    __shared__ float u_s[64];
    __shared__ float rowraw[64];
    __shared__ float colred[4][512];
    __shared__ float bs[4];

    // load this lane's static P0 slice into registers (only global P0 read of the kernel)
    uint4 pw[16];
#pragma unroll
    for (int r = 0; r < 16; r++) {
        int row = rowbase + w * 16 + r;
        pw[r] = ((const uint4*)(p0 + (((size_t)(b << 9) + row) << 9)))[lane];
    }
    for (int j = t; j < 512; j += 256) v_s[j] = MARG;
    if (t < 64) u_s[t] = MARG;
    __syncthreads();

    unsigned* myctr = &ctr[b * 16];

#pragma unroll 1
    for (int it = 0; it < NITER; ++it) {
        float vr[8];
#pragma unroll
        for (int k = 0; k < 8; k++) vr[k] = v_s[lane * 8 + k];
        float ca[8];
#pragma unroll
        for (int k = 0; k < 8; k++) ca[k] = 0.f;
#pragma unroll
        for (int r = 0; r < 16; r++) {
            float u_r = u_s[w * 16 + r];
            uint4 pwv = pw[r];
            float f[8];
            f[0] = bf2f_lo(pwv.x); f[1] = bf2f_hi(pwv.x);
            f[2] = bf2f_lo(pwv.y); f[3] = bf2f_hi(pwv.y);
            f[4] = bf2f_lo(pwv.z); f[5] = bf2f_hi(pwv.z);
            f[6] = bf2f_lo(pwv.w); f[7] = bf2f_hi(pwv.w);
            float rd = 0.f;
#pragma unroll
            for (int k = 0; k < 8; k++) { rd += f[k] * vr[k]; ca[k] += f[k] * u_r; }
            rd = wred64(rd);
            if (lane == 0) rowraw[w * 16 + r] = rd;
        }
#pragma unroll
        for (int k = 0; k < 8; k++) colred[w][lane * 8 + k] = ca[k];
        __syncthreads();                                   // rowraw + colred ready
        float* cw = colp + ((((it & 1) * 64 + b) * 8 + rb) << 9);
        for (int j = t; j < 512; j += 256) {
            float s = colred[0][j] + colred[1][j] + colred[2][j] + colred[3][j];
            __hip_atomic_store(&cw[j], s, __ATOMIC_RELAXED, __HIP_MEMORY_SCOPE_AGENT);
        }
        if (t < 64) {                                      // u update from own raw row sums
            float q = MARG / rowraw[t];
            if (!isfinite(q)) q = MARG;
            u_s[t] = q;
        }
        __syncthreads();                                   // drains vmcnt(0): partials at IF
        if (t == 0) {
            __hip_atomic_fetch_add(myctr, 1u, __ATOMIC_RELAXED, __HIP_MEMORY_SCOPE_AGENT);
            unsigned tgt = 8u * (unsigned)(it + 1);
            while (__hip_atomic_load(myctr, __ATOMIC_RELAXED, __HIP_MEMORY_SCOPE_AGENT) < tgt)
                __builtin_amdgcn_s_sleep(1);
        }
        __syncthreads();
        const float* crd = colp + ((((it & 1) * 64 + b) * 8) << 9);
        for (int j = t; j < 512; j += 256) {               // v update from 8 partials
            float raw = 0.f;
#pragma unroll
            for (int p = 0; p < 8; p++)
                raw += __hip_atomic_load(&crd[(p << 9) + j], __ATOMIC_RELAXED,
                                         __HIP_MEMORY_SCOPE_AGENT);
            float q = MARG / raw;
            if (!isfinite(q)) q = MARG;
            v_s[j] = q;
        }
        __syncthreads();
    }

    // final contraction: P = u P0 v ; C = -0.1*log(P0)
    float vr[8];
#pragma unroll
    for (int k = 0; k < 8; k++) vr[k] = v_s[lane * 8 + k];
    float acc = 0.f;
#pragma unroll
    for (int r = 0; r < 16; r++) {
        float u_r = u_s[w * 16 + r];
        uint4 pwv = pw[r];
        float f[8];
        f[0] = bf2f_lo(pwv.x); f[1] = bf2f_hi(pwv.x);
        f[2] = bf2f_lo(pwv.y); f[3] = bf2f_hi(pwv.y);
        f[4] = bf2f_lo(pwv.z); f[5] = bf2f_hi(pwv.z);
        f[6] = bf2f_lo(pwv.w); f[7] = bf2f_hi(pwv.w);
#pragma unroll
        for (int k = 0; k < 8; k++) {
            float p = f[k];
            acc += u_r * p * vr[k] * (-0.1f) * logf(p);
        }
    }
    acc = wred64(acc);
    if (lane == 0) bs[w] = acc;
    __syncthreads();
    if (t == 0) {
        float c = (bs[0] + bs[1] + bs[2] + bs[3]) * (1.0f / 64.0f);   // /B
        atomicAdd(&outf[1], c);
        atomicAdd(&outf[2], c);
    }
}

extern "C" void kernel_launch(void* const* d_in, const int* in_sizes, int n_in,
                              void* d_out, int out_size, void* d_ws, size_t ws_size,
                              hipStream_t stream) {
    const void* sg = d_in[0];
    const void* qg = d_in[1];
    const void* an = d_in[2];
    const void* bn = d_in[3];
    char* ws = (char*)d_ws;
    float* outf = (float*)d_out;                     // output dtype: float32 x3

    int*      flagp = (int*)ws;
    unsigned* ctr   = (unsigned*)(ws + 64);
    float* simg     = (float*)(ws + O_SIMG);
    float* rnsg     = (float*)(ws + O_RNSG);
    float* rnqg     = (float*)(ws + O_RNQG);
    float* rnan     = (float*)(ws + O_RNAN);
    float* rnbn     = (float*)(ws + O_RNBN);
    float* colp     = (float*)(ws + O_COLP);         // 2 banks
    unsigned short* p0 = (unsigned short*)(ws + O_P0);

    k_detect<<<1, 256, 0, stream>>>((const unsigned*)sg, flagp, outf, ctr);
    k_rnorm<<<16, 256, 0, stream>>>(sg, rnsg, 64, flagp);
    k_rnorm<<<16, 256, 0, stream>>>(qg, rnqg, 64, flagp);
    k_rnorm<<<8192, 256, 0, stream>>>(an, rnan, 32768, flagp);
    k_rnorm<<<8192, 256, 0, stream>>>(bn, rnbn, 32768, flagp);
    k_simg<<<16, 256, 0, stream>>>(sg, qg, rnsg, rnqg, simg, flagp);
    k_gloss<<<1, 256, 0, stream>>>(simg, outf);
    k_build<<<dim3(16, 64), 256, 0, stream>>>(an, bn, rnan, rnbn, p0, flagp);

    k_persist<<<512, 256, 0, stream>>>(p0, colp, ctr, outf);
}

// Round 6
// 810.791 us; speedup vs baseline: 2.5071x; 1.0979x over previous
//
#include <hip/hip_runtime.h>
#include <cstdint>
#include <cmath>

// Problem constants (fixed by reference):
//   B=64 examples, D=128 dim, NP=512 nodes/tokens per example, 100 Jacobi Sinkhorn iters.
#define NB_EX 64
#define DIMD 128
#define NP 512
#define NITER 100
constexpr float MARG = 1.0f / 512.0f;   // a = b = 1/n

// ---------- helpers ----------
__device__ __forceinline__ float bf2f_lo(unsigned w) { return __uint_as_float(w << 16); }
__device__ __forceinline__ float bf2f_hi(unsigned w) { return __uint_as_float(w & 0xFFFF0000u); }
__device__ __forceinline__ unsigned short f2bf(float f) {
    unsigned u = __float_as_uint(f);
    u += 0x7FFFu + ((u >> 16) & 1u);      // RTNE
    return (unsigned short)(u >> 16);
}
__device__ __forceinline__ float wred64(float v) {
#pragma unroll
    for (int m = 1; m < 64; m <<= 1) v += __shfl_xor(v, m, 64);
    return v;
}

// Per-block dtype self-detection (bf16-pair low halfword exponent clusters in [110,130];
// fp32 low mantissa bits hit ~8%). 256-thread blocks only. Costs one syncthreads.
__device__ __forceinline__ int self_detect(const unsigned* probe, int t) {
    __shared__ int sd_cnt[4];
    unsigned w = probe[t];
    unsigned e = (w >> 7) & 0xFFu;
    unsigned long long m = __ballot(e >= 110u && e <= 130u);
    if ((t & 63) == 0) sd_cnt[t >> 6] = __popcll(m);
    __syncthreads();
    int c = sd_cnt[0] + sd_cnt[1] + sd_cnt[2] + sd_cnt[3];
    __syncthreads();
    return c >= 128;
}

// ---------- workspace layout (bytes) ----------
#define O_SIMG   0               // 64*64 f32 (16384)
#define O_RNAN   16384           // 32768 f32 (131072)
#define O_RNBN   147456          // 32768 f32 (131072)
#define O_COLP   278528          // 2 banks x 64ex x 8blk x 512 packed u32 (2 MB)
#define O_P0     2375680         // 64*512*512 bf16 (33554432) -> total ~35.9 MB
#define COLP_BANK (64 * 8 * 512) // u32 per bank

// ---------- fused inverse L2 norms for struct_nodes + seq_tokens (65536 rows) ----------
__global__ void k_rnormAB(const void* anr, const void* bnr, float* rnan, float* rnbn) {
    int t = threadIdx.x;
    int flag = self_detect((const unsigned*)anr, t);
    int gr  = blockIdx.x * 4 + (t >> 6);      // global row 0..65535
    int lane = t & 63;
    const void* in = (gr < 32768) ? anr : bnr;
    float* rn      = (gr < 32768) ? rnan : rnbn;
    int row = gr & 32767;
    float f0, f1;
    if (flag) {
        unsigned w = ((const unsigned*)in)[row * 64 + lane];
        f0 = bf2f_lo(w); f1 = bf2f_hi(w);
    } else {
        float2 v = ((const float2*)in)[row * 64 + lane];
        f0 = v.x; f1 = v.y;
    }
    float ss = wred64(f0 * f0 + f1 * f1);
    if (lane == 0) rn[row] = 1.0f / fmaxf(sqrtf(ss), 1e-12f);
}

// ---------- global sim logits (self-detecting, self-normalizing) ----------
__global__ void k_simg(const void* sgr, const void* qgr, float* simg) {
    __shared__ float rls[128];                // [0..63]=1/||s_i||, [64..127]=1/||q_j||
    int t = threadIdx.x;
    int flag = self_detect((const unsigned*)sgr, t);
    int w = t >> 6, lane = t & 63;
    for (int rr = 0; rr < 32; rr++) {         // each wave: 32 of 128 rows
        int ri = w * 32 + rr;
        const void* base = (ri < 64) ? sgr : qgr;
        int row = ri & 63;
        float f0, f1;
        if (flag) {
            unsigned wd = ((const unsigned*)base)[row * 64 + lane];
            f0 = bf2f_lo(wd); f1 = bf2f_hi(wd);
        } else {
            float2 v = ((const float2*)base)[row * 64 + lane];
            f0 = v.x; f1 = v.y;
        }
        float ss = wred64(f0 * f0 + f1 * f1);
        if (lane == 0) rls[ri] = 1.0f / fmaxf(sqrtf(ss), 1e-12f);
    }
    __syncthreads();
    int g = blockIdx.x * 256 + t;             // 4096 = 64*64
    int i = g >> 6, j = g & 63;
    float dot = 0.f;
    if (flag) {
        const unsigned* a = (const unsigned*)sgr + i * 64;
        const unsigned* b = (const unsigned*)qgr + j * 64;
        for (int k = 0; k < 64; k++) {
            unsigned wa = a[k], wb = b[k];
            dot += bf2f_lo(wa) * bf2f_lo(wb);
            dot += bf2f_hi(wa) * bf2f_hi(wb);
        }
    } else {
        const float4* a = (const float4*)sgr + i * 32;
        const float4* b = (const float4*)qgr + j * 32;
        for (int k = 0; k < 32; k++) {
            float4 x = a[k], y = b[k];
            dot += x.x * y.x + x.y * y.y + x.z * y.z + x.w * y.w;
        }
    }
    simg[g] = dot * rls[i] * rls[64 + j] * 10.0f;   // /TEMP = *10
}

// ---------- global NT-Xent; initializes all 3 outputs (stores, not adds) ----------
__global__ void k_gloss(const float* __restrict__ simg, float* outf) {
    __shared__ float red[64];
    int i = threadIdx.x;
    if (i < 64) {
        float m = -1e30f;
        for (int j = 0; j < 64; j++) m = fmaxf(m, simg[i * 64 + j]);
        float se = 0.f;
        for (int j = 0; j < 64; j++) se += expf(simg[i * 64 + j] - m);
        float rl = simg[i * 64 + i] - (m + logf(se));
        float m2 = -1e30f;
        for (int j = 0; j < 64; j++) m2 = fmaxf(m2, simg[j * 64 + i]);
        float se2 = 0.f;
        for (int j = 0; j < 64; j++) se2 += expf(simg[j * 64 + i] - m2);
        float cl = simg[i * 64 + i] - (m2 + logf(se2));
        red[i] = rl + cl;
    }
    __syncthreads();
    if (i == 0) {
        float s = 0.f;
        for (int k = 0; k < 64; k++) s += red[k];
        float g = -s / 128.0f;
        outf[0] = g;          // global loss
        outf[1] = 0.0f;       // local loss accumulated by k_persist
        outf[2] = g;          // total = g + local (added by k_persist)
    }
}

// ---------- build P0 = exp(10*sim) bf16, per-example 512x512, 128x128 tiles ----------
__global__ void k_build(const void* anr, const void* bnr, const float* rnan, const float* rnbn,
                        unsigned short* p0) {
    int t  = threadIdx.x;
    int flag = self_detect((const unsigned*)anr, t);
    int b   = blockIdx.y;
    int r0t = (blockIdx.x >> 2) * 128;
    int c0t = (blockIdx.x & 3) * 128;
    __shared__ float As[128][33];
    __shared__ float Bs[128][33];
    int tr = t >> 4, tc = t & 15;
    float acc[8][8];
#pragma unroll
    for (int i = 0; i < 8; i++)
#pragma unroll
        for (int j = 0; j < 8; j++) acc[i][j] = 0.f;

    for (int kc = 0; kc < 4; kc++) {            // K chunks of 32
        for (int ii = 0; ii < 4; ii++) {
            int idx = t + 256 * ii;             // 0..1023 -> 128 rows x 8 float4
            int r = idx >> 3, c4 = idx & 7;
            {   // A chunk (struct_nodes)
                int grow = b * NP + r0t + r;
                float sc = rnan[grow];
                float f0, f1, f2, f3;
                if (flag) {
                    const unsigned* src = (const unsigned*)anr + ((grow * DIMD + kc * 32 + c4 * 4) >> 1);
                    unsigned w0 = src[0], w1 = src[1];
                    f0 = bf2f_lo(w0); f1 = bf2f_hi(w0); f2 = bf2f_lo(w1); f3 = bf2f_hi(w1);
                } else {
                    float4 v = *((const float4*)((const float*)anr + grow * DIMD + kc * 32 + c4 * 4));
                    f0 = v.x; f1 = v.y; f2 = v.z; f3 = v.w;
                }
                As[r][c4 * 4 + 0] = f0 * sc; As[r][c4 * 4 + 1] = f1 * sc;
                As[r][c4 * 4 + 2] = f2 * sc; As[r][c4 * 4 + 3] = f3 * sc;
            }
            {   // B chunk (seq_tokens)
                int grow = b * NP + c0t + r;
                float sc = rnbn[grow];
                float f0, f1, f2, f3;
                if (flag) {
                    const unsigned* src = (const unsigned*)bnr + ((grow * DIMD + kc * 32 + c4 * 4) >> 1);
                    unsigned w0 = src[0], w1 = src[1];
                    f0 = bf2f_lo(w0); f1 = bf2f_hi(w0); f2 = bf2f_lo(w1); f3 = bf2f_hi(w1);
                } else {
                    float4 v = *((const float4*)((const float*)bnr + grow * DIMD + kc * 32 + c4 * 4));
                    f0 = v.x; f1 = v.y; f2 = v.z; f3 = v.w;
                }
                Bs[r][c4 * 4 + 0] = f0 * sc; Bs[r][c4 * 4 + 1] = f1 * sc;
                Bs[r][c4 * 4 + 2] = f2 * sc; Bs[r][c4 * 4 + 3] = f3 * sc;
            }
        }
        __syncthreads();
        for (int kk = 0; kk < 32; kk++) {
            float av[8], bv[8];
#pragma unroll
            for (int i = 0; i < 8; i++) av[i] = As[tr * 8 + i][kk];
#pragma unroll
            for (int j = 0; j < 8; j++) bv[j] = Bs[tc * 8 + j][kk];
#pragma unroll
            for (int i = 0; i < 8; i++)
#pragma unroll
                for (int j = 0; j < 8; j++) acc[i][j] += av[i] * bv[j];
        }
        __syncthreads();
    }
#pragma unroll
    for (int i = 0; i < 8; i++) {
        int grow = b * NP + r0t + tr * 8 + i;
        unsigned short h[8];
#pragma unroll
        for (int j = 0; j < 8; j++) h[j] = f2bf(expf(acc[i][j] * 10.0f));   // exp(sim/REG)
        uint4 pk;
        pk.x = (unsigned)h[0] | ((unsigned)h[1] << 16);
        pk.y = (unsigned)h[2] | ((unsigned)h[3] << 16);
        pk.z = (unsigned)h[4] | ((unsigned)h[5] << 16);
        pk.w = (unsigned)h[6] | ((unsigned)h[7] << 16);
        *((uint4*)(p0 + ((size_t)grow * NP + c0t + tc * 8))) = pk;
    }
}

// ---------- persistent Sinkhorn: 100 Jacobi iters + final contraction, ONE kernel ----------
// R5 lesson: counter barrier = serialized fabric roundtrips (store drain -> atomic ->
// single-thread spin -> bypassing reads) = 6.8 us/iter. Fix: TAGGED DATA. Each column
// partial is ONE u32 = bf16(value)<<16 | (iter+1). Writers fire-and-forget (no drain, no
// counter); each reader batch-polls the 16 words it needs (all loads issued per retry
// round -> one roundtrip per round). Single-word pack = no tearing.
// Bank-reuse safety WITHOUT a counter: reading tag k+1 from a peer proves the peer read
// all tag-k data (its v_{k+1} depends on it), so overwriting bank k&1 at iter k+2 is safe.
// Stale-tag safety: colp zeroed via hipMemsetAsync every call; tags 1..100 never collide.
// Co-residency by capacity: 512 blocks x 256 thr, 2/CU fit trivially; P0 slice lives in
// 64 VGPRs/lane for the whole kernel.
__global__ __launch_bounds__(256, 2) void k_persist(const unsigned short* __restrict__ p0,
                                                    unsigned* __restrict__ colp,
                                                    float* __restrict__ outf) {
    int blk = blockIdx.x;
    int rb  = blk >> 6;         // 0..7
    int b   = blk & 63;         // example
    int rowbase = rb * 64;
    int t = threadIdx.x, w = t >> 6, lane = t & 63;

    __shared__ float v_s[512];
    __shared__ float u_s[64];
    __shared__ float rowraw[64];
    __shared__ float colred[4][512];
    __shared__ float bs[4];

    // load this lane's static P0 slice into registers (only global P0 read of the kernel)
    uint4 pw[16];
#pragma unroll
    for (int r = 0; r < 16; r++) {
        int row = rowbase + w * 16 + r;
        pw[r] = ((const uint4*)(p0 + (((size_t)(b << 9) + row) << 9)))[lane];
    }
    for (int j = t; j < 512; j += 256) v_s[j] = MARG;
    if (t < 64) u_s[t] = MARG;
    __syncthreads();

    int col0 = t, col1 = t + 256;

#pragma unroll 1
    for (int it = 0; it < NITER; ++it) {
        float vr[8];
#pragma unroll
        for (int k = 0; k < 8; k++) vr[k] = v_s[lane * 8 + k];
        float ca[8];
#pragma unroll
        for (int k = 0; k < 8; k++) ca[k] = 0.f;
#pragma unroll
        for (int r = 0; r < 16; r++) {
            float u_r = u_s[w * 16 + r];
            uint4 pwv = pw[r];
            float f[8];
            f[0] = bf2f_lo(pwv.x); f[1] = bf2f_hi(pwv.x);
            f[2] = bf2f_lo(pwv.y); f[3] = bf2f_hi(pwv.y);
            f[4] = bf2f_lo(pwv.z); f[5] = bf2f_hi(pwv.z);
            f[6] = bf2f_lo(pwv.w); f[7] = bf2f_hi(pwv.w);
            float rd = 0.f;
#pragma unroll
            for (int k = 0; k < 8; k++) { rd += f[k] * vr[k]; ca[k] += f[k] * u_r; }
            rd = wred64(rd);
            if (lane == 0) rowraw[w * 16 + r] = rd;
        }
#pragma unroll
        for (int k = 0; k < 8; k++) colred[w][lane * 8 + k] = ca[k];
        __syncthreads();                                   // rowraw + colred ready
        unsigned tag = (unsigned)(it + 1);
        unsigned* cw = colp + ((((it & 1) * 64 + b) * 8 + rb) << 9);
        {   // fire-and-forget tagged partials (2 per thread)
            float s0 = colred[0][col0] + colred[1][col0] + colred[2][col0] + colred[3][col0];
            float s1 = colred[0][col1] + colred[1][col1] + colred[2][col1] + colred[3][col1];
            unsigned p0w = ((unsigned)f2bf(s0) << 16) | tag;
            unsigned p1w = ((unsigned)f2bf(s1) << 16) | tag;
            __hip_atomic_store(&cw[col0], p0w, __ATOMIC_RELAXED, __HIP_MEMORY_SCOPE_AGENT);
            __hip_atomic_store(&cw[col1], p1w, __ATOMIC_RELAXED, __HIP_MEMORY_SCOPE_AGENT);
        }
        if (t < 64) {                                      // u update from own raw row sums
            float q = MARG / rowraw[t];
            if (!isfinite(q)) q = MARG;
            u_s[t] = q;
        }
        // batch-poll the 16 tagged partials this thread needs (8 per column)
        const unsigned* crd = colp + ((((it & 1) * 64 + b) * 8) << 9);
        unsigned got0[8], got1[8];
        bool ok = false;
        do {
            bool o = true;
#pragma unroll
            for (int p = 0; p < 8; p++) {
                got0[p] = __hip_atomic_load(&crd[(p << 9) + col0], __ATOMIC_RELAXED,
                                            __HIP_MEMORY_SCOPE_AGENT);
                got1[p] = __hip_atomic_load(&crd[(p << 9) + col1], __ATOMIC_RELAXED,
                                            __HIP_MEMORY_SCOPE_AGENT);
            }
#pragma unroll
            for (int p = 0; p < 8; p++)
                o = o && ((got0[p] & 0xFFFFu) == tag) && ((got1[p] & 0xFFFFu) == tag);
            if (!o) __builtin_amdgcn_s_sleep(1);
            ok = o;
        } while (!ok);
        float r0 = 0.f, r1 = 0.f;
#pragma unroll
        for (int p = 0; p < 8; p++) {
            r0 += __uint_as_float(got0[p] & 0xFFFF0000u);
            r1 += __uint_as_float(got1[p] & 0xFFFF0000u);
        }
        float q0 = MARG / r0; if (!isfinite(q0)) q0 = MARG;
        float q1 = MARG / r1; if (!isfinite(q1)) q1 = MARG;
        v_s[col0] = q0;
        v_s[col1] = q1;
        __syncthreads();
    }

    // final contraction: P = u P0 v ; C = -0.1*log(P0)
    float vr[8];
#pragma unroll
    for (int k = 0; k < 8; k++) vr[k] = v_s[lane * 8 + k];
    float acc = 0.f;
#pragma unroll
    for (int r = 0; r < 16; r++) {
        float u_r = u_s[w * 16 + r];
        uint4 pwv = pw[r];
        float f[8];
        f[0] = bf2f_lo(pwv.x); f[1] = bf2f_hi(pwv.x);
        f[2] = bf2f_lo(pwv.y); f[3] = bf2f_hi(pwv.y);
        f[4] = bf2f_lo(pwv.z); f[5] = bf2f_hi(pwv.z);
        f[6] = bf2f_lo(pwv.w); f[7] = bf2f_hi(pwv.w);
#pragma unroll
        for (int k = 0; k < 8; k++) {
            float p = f[k];
            acc += u_r * p * vr[k] * (-0.1f) * logf(p);
        }
    }
    acc = wred64(acc);
    if (lane == 0) bs[w] = acc;
    __syncthreads();
    if (t == 0) {
        float c = (bs[0] + bs[1] + bs[2] + bs[3]) * (1.0f / 64.0f);   // /B
        atomicAdd(&outf[1], c);
        atomicAdd(&outf[2], c);
    }
}

extern "C" void kernel_launch(void* const* d_in, const int* in_sizes, int n_in,
                              void* d_out, int out_size, void* d_ws, size_t ws_size,
                              hipStream_t stream) {
    const void* sg = d_in[0];
    const void* qg = d_in[1];
    const void* an = d_in[2];
    const void* bn = d_in[3];
    char* ws = (char*)d_ws;
    float* outf = (float*)d_out;                     // output dtype: float32 x3

    float* simg     = (float*)(ws + O_SIMG);
    float* rnan     = (float*)(ws + O_RNAN);
    float* rnbn     = (float*)(ws + O_RNBN);
    unsigned* colp  = (unsigned*)(ws + O_COLP);      // 2 tagged banks
    unsigned short* p0 = (unsigned short*)(ws + O_P0);

    hipMemsetAsync(colp, 0, 2 * COLP_BANK * sizeof(unsigned), stream);  // zero tags

    k_rnormAB<<<16384, 256, 0, stream>>>(an, bn, rnan, rnbn);
    k_simg<<<16, 256, 0, stream>>>(sg, qg, simg);
    k_gloss<<<1, 256, 0, stream>>>(simg, outf);
    k_build<<<dim3(16, 64), 256, 0, stream>>>(an, bn, rnan, rnbn, p0);
    k_persist<<<512, 256, 0, stream>>>(p0, colp, outf);
}